// Round 9
// baseline (507.763 us; speedup 1.0000x reference)
//
#include <hip/hip_runtime.h>
#include <stdint.h>

typedef unsigned int u32;
typedef unsigned char u8;
typedef unsigned long long u64;
typedef int v4i __attribute__((ext_vector_type(4)));

#define NB 256
#define NC 20
#define BLK 256
#define NCTR (NC * NB)              // 5120 packed counters (tot lo16 | fg hi16)
#define DUMP_BYTES (NCTR * 4)       // 20480 B per dump slot
#define FINAL_U32 (NCTR * 2)
#define OFF_CE   (FINAL_U32 * 4)
#define OFF_CNT  (OFF_CE + 4)
#define OFF_DUMPS 65536
#define RESERVED  OFF_DUMPS
#define NCHUNK 4
#define K1A_BLOCKS 1024
#define K1B_BLOCKS 256              // dump slots per chunk

// ---------------- float4 helpers ----------------
__device__ __forceinline__ float4 f4max(float4 a, float4 b) {
    return make_float4(fmaxf(a.x,b.x), fmaxf(a.y,b.y), fmaxf(a.z,b.z), fmaxf(a.w,b.w));
}
__device__ __forceinline__ float4 f4add(float4 a, float4 b) {
    return make_float4(a.x+b.x, a.y+b.y, a.z+b.z, a.w+b.w);
}
__device__ __forceinline__ float4 f4expsub(float4 a, float m) {
    return make_float4(__expf(a.x-m), __expf(a.y-m), __expf(a.z-m), __expf(a.w-m));
}
__device__ __forceinline__ u32 bin1(float e, float inv, int c, int t, float& pt) {
    float p = e * inv;
    if (c == t) pt = p;
    float err = (c == t) ? 1.0f - p : p;
    int b = (int)(err * 256.0f);
    return (u32)(b > 255 ? 255 : b);
}
__device__ __forceinline__ u32 pack4(float4 e, float inv, int cb, int t, float& pt) {
    return  bin1(e.x, inv, cb+0, t, pt)
         | (bin1(e.y, inv, cb+1, t, pt) << 8)
         | (bin1(e.z, inv, cb+2, t, pt) << 16)
         | (bin1(e.w, inv, cb+3, t, pt) << 24);
}

__device__ __forceinline__ void compute_bins(
    const float* __restrict__ logits, int idx, int t,
    u32& w0, u32& w1, u32& w2, u32& w3, u32& w4, float& pt)
{
    const float4* row = (const float4*)(logits + (size_t)idx * NC);
    float4 v0 = row[0], v1 = row[1], v2 = row[2], v3 = row[3], v4 = row[4];
    float4 m4 = f4max(f4max(v0, v1), f4max(v2, v3));
    m4 = f4max(m4, v4);
    float mx = fmaxf(fmaxf(m4.x, m4.y), fmaxf(m4.z, m4.w));
    float4 e0 = f4expsub(v0, mx);
    float4 e1 = f4expsub(v1, mx);
    float4 e2 = f4expsub(v2, mx);
    float4 e3 = f4expsub(v3, mx);
    float4 e4 = f4expsub(v4, mx);
    float4 s4 = f4add(f4add(e0, e1), f4add(e2, e3));
    s4 = f4add(s4, e4);
    float s = (s4.x + s4.y) + (s4.z + s4.w);
    float inv = 1.0f / s;
    pt = 1.0f;
    w0 = pack4(e0, inv, 0,  t, pt);
    w1 = pack4(e1, inv, 4,  t, pt);
    w2 = pack4(e2, inv, 8,  t, pt);
    w3 = pack4(e3, inv, 12, t, pt);
    w4 = pack4(e4, inv, 16, t, pt);
}

// ---------------- k1a_c: softmax + CE + bin write for chunk [start,end) ----------------
__global__ __launch_bounds__(BLK) void k1a_chunk(
    const float* __restrict__ logits, const int* __restrict__ tgt,
    int start, int end,
    u32* __restrict__ aos16, u32* __restrict__ w4s, u8* __restrict__ t8,
    float* __restrict__ ce_sum, u32* __restrict__ valid_cnt)
{
    int tid = blockIdx.x * BLK + threadIdx.x;
    int stride = K1A_BLOCKS * BLK;
    float ce_part = 0.f;
    u32   cnt_part = 0;

    for (int idx = start + tid; idx < end; idx += stride) {
        int t = tgt[idx];
        u32 w0, w1, w2, w3, w4; float pt;
        compute_bins(logits, idx, t, w0, w1, w2, w3, w4, pt);
        int rel = idx - start;
        v4i q = { (int)w0, (int)w1, (int)w2, (int)w3 };
        *(v4i*)(aos16 + (size_t)rel * 4) = q;
        w4s[rel] = w4;
        t8[rel]  = (u8)t;
        if (t != 0) { ce_part -= __logf(pt); cnt_part++; }
    }

    #pragma unroll
    for (int off = 32; off > 0; off >>= 1) {
        ce_part  += __shfl_down(ce_part, off);
        cnt_part += __shfl_down(cnt_part, off);
    }
    if ((threadIdx.x & 63) == 0) {
        atomicAdd(ce_sum, ce_part);
        atomicAdd(valid_cnt, cnt_part);
    }
}

// ---------------- k1b_c: histogram chunk's bins into LDS, dump ----------------
__global__ __launch_bounds__(BLK) void k1b_chunk(
    const u32* __restrict__ aos16, const u32* __restrict__ w4s, const u8* __restrict__ t8,
    int count, u32* __restrict__ dumps /* already offset to this chunk's slots */)
{
    __shared__ u32 h[NCTR];
    for (int i = threadIdx.x; i < NCTR; i += BLK) h[i] = 0;
    __syncthreads();

    int tid = blockIdx.x * BLK + threadIdx.x;
    int stride = K1B_BLOCKS * BLK;
    for (int rel = tid; rel < count; rel += stride) {
        int4 q = *(const int4*)(aos16 + (size_t)rel * 4);
        u32 w4 = w4s[rel];
        int t = t8[rel];
        u32 w[5] = { (u32)q.x, (u32)q.y, (u32)q.z, (u32)q.w, w4 };
        #pragma unroll
        for (int j = 0; j < 5; ++j) {
            #pragma unroll
            for (int k = 0; k < 4; ++k) {
                int c = j * 4 + k;
                u32 b = (w[j] >> (8 * k)) & 255u;
                atomicAdd(&h[(u32)c * 256u + b], (c == t) ? 0x10001u : 1u);
            }
        }
    }

    __syncthreads();
    u32* d = dumps + (size_t)blockIdx.x * NCTR;
    for (int i = threadIdx.x; i < NCTR; i += BLK) d[i] = h[i];
}

// ---------------- k2a: reduce + unpack dumps ----------------
__global__ __launch_bounds__(256) void k2a_reduce(
    const u32* __restrict__ dumps, u32* __restrict__ final_hist, int nblk, int chunk)
{
    int counter = (blockIdx.x % 20) * 256 + threadIdx.x;   // 20*256 == 5120
    int part    = blockIdx.x / 20;
    int b0 = part * chunk;
    int b1 = b0 + chunk; if (b1 > nblk) b1 = nblk;
    u32 lo = 0, hi = 0;
    for (int blk = b0; blk < b1; ++blk) {
        u32 v = dumps[(size_t)blk * NCTR + counter];
        lo += v & 0xFFFFu;
        hi += v >> 16;
    }
    if (lo) atomicAdd(&final_hist[counter], lo);
    if (hi) atomicAdd(&final_hist[NCTR + counter], hi);
}

// ---------------- k2b: per-class descending bin scan + finalize ----------------
__device__ __forceinline__ float jac_of(float gts, u32 cf, u32 ct)
{
    float I = gts - (float)cf;
    float U = gts + (float)ct - (float)cf;
    return 1.0f - I / U;
}

__global__ __launch_bounds__(256) void k2b_final(
    const u32* __restrict__ final_hist, const float* __restrict__ ce_sum,
    const u32* __restrict__ valid_cnt, float* __restrict__ outp)
{
    __shared__ u64 sc[NB];
    __shared__ float red[NB];
    int t = threadIdx.x;

    float lovsum = 0.f;
    int prescnt = 0;

    for (int c = 0; c < NC; ++c) {
        int b = NB - 1 - t;
        u32 tot = final_hist[c * NB + b];
        u32 fg  = final_hist[NCTR + c * NB + b];
        u64 v = ((u64)fg << 32) | (u64)tot;

        sc[t] = v;
        __syncthreads();
        for (int off = 1; off < NB; off <<= 1) {
            u64 add = (t >= off) ? sc[t - off] : 0ull;
            __syncthreads();
            sc[t] += add;
            __syncthreads();
        }
        u64 incl  = sc[t];
        u64 total = sc[NB - 1];
        float gts = (float)(u32)(total >> 32);

        float contrib = 0.f;
        if (gts > 0.f) {
            u64 excl = incl - v;
            float jE = jac_of(gts, (u32)(excl >> 32), (u32)excl);
            float jI = jac_of(gts, (u32)(incl >> 32), (u32)incl);
            float eb = ((float)b + 0.5f) * (1.0f / (float)NB);
            contrib = eb * (jI - jE);
        }

        red[t] = contrib;
        __syncthreads();
        #pragma unroll
        for (int off = NB / 2; off > 0; off >>= 1) {
            if (t < off) red[t] += red[t + off];
            __syncthreads();
        }
        if (t == 0 && gts > 0.f) { lovsum += red[0]; prescnt++; }
        __syncthreads();
    }

    if (t == 0) {
        u32 vc = *valid_cnt; if (vc < 1u) vc = 1u;
        float ce = *ce_sum / (float)vc;
        int pc = prescnt < 1 ? 1 : prescnt;
        float lov = lovsum / (float)pc;
        outp[0] = 2.0f * ce;
        outp[1] = 6.0f * lov;
    }
}

// ---------------- launch ----------------
extern "C" void kernel_launch(void* const* d_in, const int* in_sizes, int n_in,
                              void* d_out, int out_size, void* d_ws, size_t ws_size,
                              hipStream_t stream)
{
    const float* logits = (const float*)d_in[0];
    const int*   tgt    = (const int*)d_in[1];
    int P = in_sizes[1];

    char* ws = (char*)d_ws;
    u32*  final_hist = (u32*)ws;
    float* ce_sum    = (float*)(ws + OFF_CE);
    u32*  valid_cnt  = (u32*)(ws + OFF_CNT);
    u32*  dumps      = (u32*)(ws + OFF_DUMPS);     // NCHUNK*K1B_BLOCKS slots

    int nslots = NCHUNK * K1B_BLOCKS;              // 1024 dump slots
    size_t off_bins = (size_t)OFF_DUMPS + (size_t)nslots * DUMP_BYTES;   // ~21 MB

    int chunk_max = (P + NCHUNK - 1) / NCHUNK;     // 500000 for P=2M
    u32* aos16 = (u32*)(ws + off_bins);                                   // 16 B/pt (reused)
    u32* w4s   = (u32*)(ws + off_bins + (size_t)16 * chunk_max);          // 4 B/pt
    u8*  t8    = (u8*) (ws + off_bins + (size_t)20 * chunk_max);          // 1 B/pt

    hipMemsetAsync(d_ws, 0, RESERVED, stream);

    for (int c = 0; c < NCHUNK; ++c) {
        int start = c * chunk_max; if (start > P) start = P;
        int end   = start + chunk_max; if (end > P) end = P;
        int count = end - start;
        if (count <= 0) break;
        hipLaunchKernelGGL(k1a_chunk, dim3(K1A_BLOCKS), dim3(BLK), 0, stream,
                           logits, tgt, start, end, aos16, w4s, t8, ce_sum, valid_cnt);
        hipLaunchKernelGGL(k1b_chunk, dim3(K1B_BLOCKS), dim3(BLK), 0, stream,
                           aos16, w4s, t8, count, dumps + (size_t)c * K1B_BLOCKS * NCTR);
    }

    int split = 32;
    int chunk = (nslots + split - 1) / split;
    hipLaunchKernelGGL(k2a_reduce, dim3(20 * split), dim3(256), 0, stream,
                       dumps, final_hist, nslots, chunk);
    hipLaunchKernelGGL(k2b_final, dim3(1), dim3(NB), 0, stream,
                       final_hist, ce_sum, valid_cnt, (float*)d_out);
}